// Round 14
// baseline (791.313 us; speedup 1.0000x reference)
//
#include <hip/hip_runtime.h>
#include <stdint.h>

// proj = einsum('bit,ih->tbh', x, W); scan: h=relu(p+0.8h(1-y)); y=thr(h+b,1).
// B=64, K=512, T=512, H=1024 fp32. Output: final y (64x1024).
//
// R19: wave decorrelation + halved sync. Seven schedules (R7-R18) pin
// MfmaUtil at 41+-1%; the sweep eliminated LDS traffic (x2 -> null),
// read-ahead depth (null), convert VALU (x0.5 -> null), occupancy (x2 ->
// null), dep chains, spills. The never-varied invariant: all 8 waves run
// identical code between per-kt barriers -> phase-correlated converts/
// LDS-stalls/barrier-waits; per-kt time ~= SUM of pipe times, not max.
// This round, on the R16 base (bit-exact):
//  1) B in a 4-slot ring (4x32KB; slot kt&3; stage(kt+2) issued during
//     kt -> every slot's DMA crosses >=1 barrier before first read).
//     P[64][256] aliases slots 2,3 (dead at t-tile end).
//  2) ONE s_waitcnt(0)+barrier per TWO kt (after odd kt). Within a pair
//     waves drift; slot-disjointness holds under +-1-kt drift (writer
//     hits (kt+2)%4; readers hold kt%4,(kt+1)%4).
//  3) anti-correlated col order: odd waves traverse ni 15->0 (even
//     0->15) so neighboring waves' reads/MFMA interleave, not collide.
// Per-element MFMA sequence unchanged -> bit-identical; absmax 0.03125.
// Geometry = R16: 8x1 waves (32t x 256h), A direct-from-global + in-reg
// split, W-only prepass (2MB ws), epilogue P+swizzle, scan.

#define NB 64
#define NK 512
#define NT 512
#define NH 1024

#define TB 256     // t per block tile
#define HB 256     // h per block tile
#define KK 32      // k per step
#define NKT (NK / KK)   // 16

typedef _Float16 h8_t __attribute__((ext_vector_type(8)));
typedef float    f4_t __attribute__((ext_vector_type(4)));

#define AS1 __attribute__((address_space(1)))
#define AS3 __attribute__((address_space(3)))

__device__ __forceinline__ void async_copy16(const void* g, void* l) {
    __builtin_amdgcn_global_load_lds((const AS1 uint32_t*)g, (AS3 uint32_t*)l, 16, 0, 0);
}

__device__ __forceinline__ void wait_all_barrier() {
    __builtin_amdgcn_s_waitcnt(0);   // vmcnt(0) expcnt(0) lgkmcnt(0)
    __syncthreads();
}

// ---- W-only pre-pass: fp32 [512][1024] -> fp16 hi/lo in fragment order
__global__ __launch_bounds__(256) void split_w(
    const float* __restrict__ Wm, _Float16* __restrict__ whi,
    _Float16* __restrict__ wlo)
{
    const int tid = threadIdx.x;
    const int cq  = tid & 15;     // col quad 0..15
    const int u   = tid >> 4;     // row octet 0..15

    const int bx = blockIdx.x;    // 0..15
    const int by = blockIdx.y;    // 0..3
    const int C  = NH;
    const int col0 = bx * 64;
    const int row0 = by * 128;
    const int ktbase = by * 4;

    const float* s = Wm + (size_t)(row0 + u * 8) * C + col0 + cq * 4;

    f4_t v[8];
    #pragma unroll
    for (int j = 0; j < 8; ++j)
        v[j] = *(const f4_t*)(s + (size_t)j * C);

    const int kt = ktbase + (u >> 2);
    const int ck = u & 3;

    #pragma unroll
    for (int i = 0; i < 4; ++i) {
        h8_t hi, lo;
        #pragma unroll
        for (int j = 0; j < 8; ++j) {
            float f = v[j][i] * 64.0f;       // 2^6 pre-scale
            _Float16 hh = (_Float16)f;
            hi[j] = hh;
            lo[j] = (_Float16)(f - (float)hh);
        }
        const int col = col0 + cq * 4 + i;
        const int ckp = ck ^ ((col >> 1) & 3);
        const size_t off = ((size_t)kt * C + col) * 32 + (size_t)ckp * 8;
        *(h8_t*)(whi + off) = hi;
        *(h8_t*)(wlo + off) = lo;
    }
}

// ---------------- main fused kernel (R19: 4-ring, pair-barrier, stagger) ------
__global__ __launch_bounds__(512, 2) void fused_main(
    const float* __restrict__ X,
    const _Float16* __restrict__ whi, const _Float16* __restrict__ wlo,
    const float* __restrict__ bias, float* __restrict__ out)
{
    // B ring: 4 slots x [hi/lo][8192] halfs = 4 x 32 KB = 128 KB.
    __shared__ __align__(16) _Float16 SB[4][2][HB * KK];
    // Epilogue P[64][256] fp32 (64 KB) aliases slots 2+3 (contiguous).
    float* Pf = (float*)&SB[2][0][0];

    const int tid  = threadIdx.x;
    const int lane = tid & 63;
    const int wid  = tid >> 6;     // 0..7 = t octant (32 rows each)
    const int l15  = lane & 15;
    const int lq   = lane >> 4;    // 0..3

    const int b  = blockIdx.x;
    const int h0 = blockIdx.y * HB;

    // B fragment LDS offset (halfs); chunk swizzle matches prepass.
    const int sw   = (l15 >> 1) & 3;
    const int boff = (l15 * 4 + (lq ^ sw)) * 8;   // + ni*512, ni 0..15

    float hs = 0.0f, ys = 0.0f, bv = 0.0f;
    if (tid < HB) bv = bias[h0 + tid];

    const float INV_SCALE = 1.0f / 4096.0f;   // undo 2^6 x 2^6 operand scales

    auto stage_B = [&](int kt, int slot) {    // 4 DMA instrs / thread
        const _Float16* gb_hi = whi + ((size_t)kt * NH + h0) * KK;
        const _Float16* gb_lo = wlo + ((size_t)kt * NH + h0) * KK;
        #pragma unroll
        for (int c = 0; c < 2; ++c) {
            const int ch = tid + c * 512;
            async_copy16(gb_hi + ch * 8, &SB[slot][0][ch * 8]);
            async_copy16(gb_lo + ch * 8, &SB[slot][1][ch * 8]);
        }
    };

    // A fragment slice, direct from global (no dup across waves).
    // af[mi][j] = X[b][kt*32 + lq*8 + j][tt0 + wid*32 + mi*16 + l15]
    float af[2][8];
    auto loadA = [&](int tt0_, int kt) {
        const float* g = X + ((size_t)(b * NK + kt * KK + lq * 8)) * NT
                           + tt0_ + wid * 32 + l15;
        #pragma unroll
        for (int mi = 0; mi < 2; ++mi)
            #pragma unroll
            for (int j = 0; j < 8; ++j)
                af[mi][j] = g[(size_t)j * NT + mi * 16];
    };

    h8_t ah[2], al[2];
    auto convertA = [&]() {
        #pragma unroll
        for (int mi = 0; mi < 2; ++mi)
            #pragma unroll
            for (int j = 0; j < 8; ++j) {
                float f = af[mi][j] * 64.0f;     // bit-identical split
                _Float16 hh = (_Float16)f;
                ah[mi][j] = hh;
                al[mi][j] = (_Float16)(f - (float)hh);
            }
    };

    // one ni-column: 6 MFMAs, mode-outer / mi-inner (bit-exact per-acc order)
    f4_t acc[2][16];
    auto mfma_col = [&](int slot, int ni) {
        h8_t bh = *(const h8_t*)(&SB[slot][0][boff + ni * 512]);
        h8_t bl = *(const h8_t*)(&SB[slot][1][boff + ni * 512]);
        #pragma unroll
        for (int mi = 0; mi < 2; ++mi)
            acc[mi][ni] = __builtin_amdgcn_mfma_f32_16x16x32_f16(ah[mi], bh, acc[mi][ni], 0, 0, 0);
        #pragma unroll
        for (int mi = 0; mi < 2; ++mi)
            acc[mi][ni] = __builtin_amdgcn_mfma_f32_16x16x32_f16(ah[mi], bl, acc[mi][ni], 0, 0, 0);
        #pragma unroll
        for (int mi = 0; mi < 2; ++mi)
            acc[mi][ni] = __builtin_amdgcn_mfma_f32_16x16x32_f16(al[mi], bh, acc[mi][ni], 0, 0, 0);
    };

    // prologue: first two kt's B DMA into slots 0,1 + A(0) register loads
    stage_B(0, 0);
    stage_B(1, 1);
    loadA(0, 0);

    for (int tt0 = 0; tt0 < NT; tt0 += TB) {
        #pragma unroll
        for (int mi = 0; mi < 2; ++mi)
            #pragma unroll
            for (int ni = 0; ni < 16; ++ni) {
                f4_t z = {0.f, 0.f, 0.f, 0.f};
                acc[mi][ni] = z;
            }

        wait_all_barrier();   // prologue DMAs landed block-wide; af landed

        for (int kt = 0; kt < NKT; ++kt) {
            const int slot = kt & 3;

            convertA();                                    // af(kt) (compiler waits)
            if (kt + 1 < NKT) loadA(tt0, kt + 1);          // refill af
            if (kt + 2 < NKT) stage_B(kt + 2, (kt + 2) & 3);  // ring DMA

            __builtin_amdgcn_s_setprio(1);
            #pragma unroll
            for (int i = 0; i < 16; ++i) {
                const int ni = (wid & 1) ? (15 - i) : i;   // anti-correlated order
                mfma_col(slot, ni);
            }
            __builtin_amdgcn_s_setprio(0);

            // ONE drain+barrier per pair: waves drift within the pair.
            // stage(kt+1 pair slots) issued >=0.5-1.5 kt earlier -> cheap.
            if (kt & 1) wait_all_barrier();
        }

        // all slots dead here (final pair-barrier drained reads + DMAs).
        // Pre-issue next t-tile's B(0),B(1) into slots 0,1 (P is slots 2,3)
        // so DMA flies under the epilogue.
        if (tt0 + TB < NT) {
            stage_B(0, 0);
            stage_B(1, 1);
        }

        // epilogue: 4 t-subtiles x 64 rows; P[64][256] fp32 on slots 2+3.
        // Rows [sub*64, sub*64+64) from waves wid = 2*sub, 2*sub+1.
        // Swizzle col' = col ^ (((row>>2)&1)<<4); writer key (lq&1) ==
        // reader key ((m>>2)&1).
        #pragma unroll 1
        for (int sub = 0; sub < 4; ++sub) {
            if ((wid >> 1) == sub) {
                #pragma unroll
                for (int mi = 0; mi < 2; ++mi)
                    #pragma unroll
                    for (int ni = 0; ni < 16; ++ni)
                        #pragma unroll
                        for (int r2 = 0; r2 < 4; ++r2) {
                            const int rloc = (wid & 1) * 32 + mi * 16 + lq * 4 + r2;
                            const int col  = (ni * 16 + l15) ^ ((lq & 1) << 4);
                            Pf[rloc * 256 + col] = acc[mi][ni][r2] * INV_SCALE;
                        }
            }
            __syncthreads();
            if (tid < HB) {
                const int cc2 = tid;   // h within block tile, 0..255
                #pragma unroll 8
                for (int m = 0; m < 64; ++m) {
                    float p = Pf[m * 256 + (cc2 ^ (((m >> 2) & 1) << 4))];
                    float pre = p + 0.8f * hs * (1.0f - ys);
                    hs = pre > 0.0f ? pre : 0.0f;
                    float z = hs + bv;
                    ys = (z > 1.0f) ? z : 0.0f;
                }
            }
            __syncthreads();   // scan done before next sub overwrites P
        }

        // next t-tile's A loads after the epilogue (af regs dead during it;
        // avoids R13's hold-across-epilogue spill). Landing covered by the
        // t-loop-top wait_all_barrier.
        if (tt0 + TB < NT)
            loadA(tt0 + TB, 0);
    }

    if (tid < HB)
        out[(size_t)b * NH + h0 + tid] = ys;
}

extern "C" void kernel_launch(void* const* d_in, const int* in_sizes, int n_in,
                              void* d_out, int out_size, void* d_ws, size_t ws_size,
                              hipStream_t stream) {
    const float* x    = (const float*)d_in[0];  // [64][512][512]
    const float* W    = (const float*)d_in[1];  // [512][1024]
    const float* bias = (const float*)d_in[2];  // [1024]
    float* out = (float*)d_out;

    _Float16* whi = (_Float16*)d_ws;            // 1 MB
    _Float16* wlo = whi + (size_t)NK * NH;      // 1 MB

    split_w<<<dim3(16, 4), 256, 0, stream>>>(W, whi, wlo);
    fused_main<<<dim3(NB, NH / HB), 512, 0, stream>>>(x, whi, wlo, bias, out);
}

// Round 15
// 213.489 us; speedup vs baseline: 3.7066x; 3.7066x over previous
//
#include <hip/hip_runtime.h>
#include <stdint.h>

// proj = einsum('bit,ih->tbh', x, W); scan: h=relu(p+0.8h(1-y)); y=thr(h+b,1).
// B=64, K=512, T=512, H=1024 fp32. Output: final y (64x1024).
//
// R20: R19 retry with the rule-#20 bug fixed. R19's 733us was NOT the
// decorrelation theory failing: `ni = (wid&1) ? 15-i : i` made acc[][]
// runtime-indexed -> compiler spilled all 128 acc regs to scratch
// (WRITE_SIZE 2.2GB, FETCH 1.16GB). Fix: hoist the wave-parity branch
// OUTSIDE the unrolled loop — both sides have compile-time ni (branch is
// wave-uniform; cluster code x2, harmless). Everything else = R19:
//  - B 4-slot ring (slot kt&3; stage(kt+2) issued during kt; P aliases
//    slots 2,3). Readers hold {kt,kt+1}&3, writer hits (kt+2)&3 ->
//    disjoint under intra-pair drift; pair-end s_waitcnt(0)+barrier
//    separates slot recycles.
//  - ONE drain+barrier per TWO kt (waves drift within a pair).
//  - anti-correlated col order: even waves ni 0->15, odd 15->0.
// Per-element MFMA sequence unchanged -> bit-identical; absmax 0.03125.
// Geometry = R16: 8x1 waves (32t x 256h), A direct-from-global + in-reg
// split, W-only prepass (2MB ws), epilogue P+swizzle, scan.

#define NB 64
#define NK 512
#define NT 512
#define NH 1024

#define TB 256     // t per block tile
#define HB 256     // h per block tile
#define KK 32      // k per step
#define NKT (NK / KK)   // 16

typedef _Float16 h8_t __attribute__((ext_vector_type(8)));
typedef float    f4_t __attribute__((ext_vector_type(4)));

#define AS1 __attribute__((address_space(1)))
#define AS3 __attribute__((address_space(3)))

__device__ __forceinline__ void async_copy16(const void* g, void* l) {
    __builtin_amdgcn_global_load_lds((const AS1 uint32_t*)g, (AS3 uint32_t*)l, 16, 0, 0);
}

__device__ __forceinline__ void wait_all_barrier() {
    __builtin_amdgcn_s_waitcnt(0);   // vmcnt(0) expcnt(0) lgkmcnt(0)
    __syncthreads();
}

// ---- W-only pre-pass: fp32 [512][1024] -> fp16 hi/lo in fragment order
__global__ __launch_bounds__(256) void split_w(
    const float* __restrict__ Wm, _Float16* __restrict__ whi,
    _Float16* __restrict__ wlo)
{
    const int tid = threadIdx.x;
    const int cq  = tid & 15;     // col quad 0..15
    const int u   = tid >> 4;     // row octet 0..15

    const int bx = blockIdx.x;    // 0..15
    const int by = blockIdx.y;    // 0..3
    const int C  = NH;
    const int col0 = bx * 64;
    const int row0 = by * 128;
    const int ktbase = by * 4;

    const float* s = Wm + (size_t)(row0 + u * 8) * C + col0 + cq * 4;

    f4_t v[8];
    #pragma unroll
    for (int j = 0; j < 8; ++j)
        v[j] = *(const f4_t*)(s + (size_t)j * C);

    const int kt = ktbase + (u >> 2);
    const int ck = u & 3;

    #pragma unroll
    for (int i = 0; i < 4; ++i) {
        h8_t hi, lo;
        #pragma unroll
        for (int j = 0; j < 8; ++j) {
            float f = v[j][i] * 64.0f;       // 2^6 pre-scale
            _Float16 hh = (_Float16)f;
            hi[j] = hh;
            lo[j] = (_Float16)(f - (float)hh);
        }
        const int col = col0 + cq * 4 + i;
        const int ckp = ck ^ ((col >> 1) & 3);
        const size_t off = ((size_t)kt * C + col) * 32 + (size_t)ckp * 8;
        *(h8_t*)(whi + off) = hi;
        *(h8_t*)(wlo + off) = lo;
    }
}

// ---------------- main fused kernel (R20: ring + pair-barrier, static ni) -----
__global__ __launch_bounds__(512, 2) void fused_main(
    const float* __restrict__ X,
    const _Float16* __restrict__ whi, const _Float16* __restrict__ wlo,
    const float* __restrict__ bias, float* __restrict__ out)
{
    // B ring: 4 slots x [hi/lo][8192] halfs = 4 x 32 KB = 128 KB.
    __shared__ __align__(16) _Float16 SB[4][2][HB * KK];
    // Epilogue P[64][256] fp32 (64 KB) aliases slots 2+3 (contiguous).
    float* Pf = (float*)&SB[2][0][0];

    const int tid  = threadIdx.x;
    const int lane = tid & 63;
    const int wid  = tid >> 6;     // 0..7 = t octant (32 rows each)
    const int l15  = lane & 15;
    const int lq   = lane >> 4;    // 0..3

    const int b  = blockIdx.x;
    const int h0 = blockIdx.y * HB;

    // B fragment LDS offset (halfs); chunk swizzle matches prepass.
    const int sw   = (l15 >> 1) & 3;
    const int boff = (l15 * 4 + (lq ^ sw)) * 8;   // + ni*512, ni 0..15

    float hs = 0.0f, ys = 0.0f, bv = 0.0f;
    if (tid < HB) bv = bias[h0 + tid];

    const float INV_SCALE = 1.0f / 4096.0f;   // undo 2^6 x 2^6 operand scales

    auto stage_B = [&](int kt, int slot) {    // 4 DMA instrs / thread
        const _Float16* gb_hi = whi + ((size_t)kt * NH + h0) * KK;
        const _Float16* gb_lo = wlo + ((size_t)kt * NH + h0) * KK;
        #pragma unroll
        for (int c = 0; c < 2; ++c) {
            const int ch = tid + c * 512;
            async_copy16(gb_hi + ch * 8, &SB[slot][0][ch * 8]);
            async_copy16(gb_lo + ch * 8, &SB[slot][1][ch * 8]);
        }
    };

    // A fragment slice, direct from global (no dup across waves).
    // af[mi][j] = X[b][kt*32 + lq*8 + j][tt0 + wid*32 + mi*16 + l15]
    float af[2][8];
    auto loadA = [&](int tt0_, int kt) {
        const float* g = X + ((size_t)(b * NK + kt * KK + lq * 8)) * NT
                           + tt0_ + wid * 32 + l15;
        #pragma unroll
        for (int mi = 0; mi < 2; ++mi)
            #pragma unroll
            for (int j = 0; j < 8; ++j)
                af[mi][j] = g[(size_t)j * NT + mi * 16];
    };

    h8_t ah[2], al[2];
    auto convertA = [&]() {
        #pragma unroll
        for (int mi = 0; mi < 2; ++mi)
            #pragma unroll
            for (int j = 0; j < 8; ++j) {
                float f = af[mi][j] * 64.0f;     // bit-identical split
                _Float16 hh = (_Float16)f;
                ah[mi][j] = hh;
                al[mi][j] = (_Float16)(f - (float)hh);
            }
    };

    // one ni-column: 6 MFMAs, mode-outer / mi-inner (bit-exact per-acc order).
    // ni must be COMPILE-TIME at every call site (rule #20).
    f4_t acc[2][16];
    auto mfma_col = [&](int slot, int ni) {
        h8_t bh = *(const h8_t*)(&SB[slot][0][boff + ni * 512]);
        h8_t bl = *(const h8_t*)(&SB[slot][1][boff + ni * 512]);
        #pragma unroll
        for (int mi = 0; mi < 2; ++mi)
            acc[mi][ni] = __builtin_amdgcn_mfma_f32_16x16x32_f16(ah[mi], bh, acc[mi][ni], 0, 0, 0);
        #pragma unroll
        for (int mi = 0; mi < 2; ++mi)
            acc[mi][ni] = __builtin_amdgcn_mfma_f32_16x16x32_f16(ah[mi], bl, acc[mi][ni], 0, 0, 0);
        #pragma unroll
        for (int mi = 0; mi < 2; ++mi)
            acc[mi][ni] = __builtin_amdgcn_mfma_f32_16x16x32_f16(al[mi], bh, acc[mi][ni], 0, 0, 0);
    };

    // prologue: first two kt's B DMA into slots 0,1 + A(0) register loads
    stage_B(0, 0);
    stage_B(1, 1);
    loadA(0, 0);

    for (int tt0 = 0; tt0 < NT; tt0 += TB) {
        #pragma unroll
        for (int mi = 0; mi < 2; ++mi)
            #pragma unroll
            for (int ni = 0; ni < 16; ++ni) {
                f4_t z = {0.f, 0.f, 0.f, 0.f};
                acc[mi][ni] = z;
            }

        wait_all_barrier();   // prologue DMAs landed block-wide; af landed

        for (int kt = 0; kt < NKT; ++kt) {
            const int slot = kt & 3;

            convertA();                                    // af(kt) (compiler waits)
            if (kt + 1 < NKT) loadA(tt0, kt + 1);          // refill af
            if (kt + 2 < NKT) stage_B(kt + 2, (kt + 2) & 3);  // ring DMA

            __builtin_amdgcn_s_setprio(1);
            // anti-correlated traversal, STATIC ni on both sides
            // (wave-uniform branch; no divergence, no dynamic indexing)
            if (wid & 1) {
                #pragma unroll
                for (int i = 0; i < 16; ++i)
                    mfma_col(slot, 15 - i);
            } else {
                #pragma unroll
                for (int i = 0; i < 16; ++i)
                    mfma_col(slot, i);
            }
            __builtin_amdgcn_s_setprio(0);

            // ONE drain+barrier per pair: waves drift within the pair.
            if (kt & 1) wait_all_barrier();
        }

        // all slots dead here (final pair-barrier drained reads + DMAs).
        // Pre-issue next t-tile's B(0),B(1) into slots 0,1 (P is slots 2,3)
        // so DMA flies under the epilogue.
        if (tt0 + TB < NT) {
            stage_B(0, 0);
            stage_B(1, 1);
        }

        // epilogue: 4 t-subtiles x 64 rows; P[64][256] fp32 on slots 2+3.
        // Rows [sub*64, sub*64+64) from waves wid = 2*sub, 2*sub+1.
        // Swizzle col' = col ^ (((row>>2)&1)<<4); writer key (lq&1) ==
        // reader key ((m>>2)&1).
        #pragma unroll 1
        for (int sub = 0; sub < 4; ++sub) {
            if ((wid >> 1) == sub) {
                #pragma unroll
                for (int mi = 0; mi < 2; ++mi)
                    #pragma unroll
                    for (int ni = 0; ni < 16; ++ni)
                        #pragma unroll
                        for (int r2 = 0; r2 < 4; ++r2) {
                            const int rloc = (wid & 1) * 32 + mi * 16 + lq * 4 + r2;
                            const int col  = (ni * 16 + l15) ^ ((lq & 1) << 4);
                            Pf[rloc * 256 + col] = acc[mi][ni][r2] * INV_SCALE;
                        }
            }
            __syncthreads();
            if (tid < HB) {
                const int cc2 = tid;   // h within block tile, 0..255
                #pragma unroll 8
                for (int m = 0; m < 64; ++m) {
                    float p = Pf[m * 256 + (cc2 ^ (((m >> 2) & 1) << 4))];
                    float pre = p + 0.8f * hs * (1.0f - ys);
                    hs = pre > 0.0f ? pre : 0.0f;
                    float z = hs + bv;
                    ys = (z > 1.0f) ? z : 0.0f;
                }
            }
            __syncthreads();   // scan done before next sub overwrites P
        }

        // next t-tile's A loads after the epilogue (af regs dead during it).
        // Landing covered by the t-loop-top wait_all_barrier.
        if (tt0 + TB < NT)
            loadA(tt0 + TB, 0);
    }

    if (tid < HB)
        out[(size_t)b * NH + h0 + tid] = ys;
}

extern "C" void kernel_launch(void* const* d_in, const int* in_sizes, int n_in,
                              void* d_out, int out_size, void* d_ws, size_t ws_size,
                              hipStream_t stream) {
    const float* x    = (const float*)d_in[0];  // [64][512][512]
    const float* W    = (const float*)d_in[1];  // [512][1024]
    const float* bias = (const float*)d_in[2];  // [1024]
    float* out = (float*)d_out;

    _Float16* whi = (_Float16*)d_ws;            // 1 MB
    _Float16* wlo = whi + (size_t)NK * NH;      // 1 MB

    split_w<<<dim3(16, 4), 256, 0, stream>>>(W, whi, wlo);
    fused_main<<<dim3(NB, NH / HB), 512, 0, stream>>>(x, whi, wlo, bias, out);
}

// Round 16
// 179.860 us; speedup vs baseline: 4.3996x; 1.1870x over previous
//
#include <hip/hip_runtime.h>
#include <stdint.h>

// proj = einsum('bit,ih->tbh', x, W); scan: h=relu(p+0.8h(1-y)); y=thr(h+b,1).
// B=64, K=512, T=512, H=1024 fp32. Output: final y (64x1024).
//
// R21: clean halved-sync test. R19 (dyn acc index -> full spill, 733us)
// and R20 (duplicated MFMA cluster -> 75MB spill, 140us) both measured
// codegen artifacts, not the decorrelation theory. This round changes
// ONE thing vs R16 (the proven 111us/VGPR-112/no-spill base): B dbuf ->
// 4-slot ring (slot kt&3; stage(kt+2) issued during kt) with ONE
// s_waitcnt(0)+barrier per TWO kt. Single cluster path, ascending ni
// (no duplication -> no spill). Ledger: slot s rewritten at kt was last
// read at kt-2; a pair-barrier always lies between (end of kt-2 if kt
// odd, end of kt-1 if kt even). Slot kt&3's DMA (issued kt-2) is always
// drained by the last pair-barrier before kt. Prologue: slots 0,1 +
// t-tile-top full drain. Epilogue P[64][256] aliases slots 2,3; next-
// tile prologue targets slots 0,1 under the epilogue. Halves barriers
// (16->8 per t-tile); waves drift up to one kt between drains.
// Per-element MFMA order unchanged -> bit-identical; absmax 0.03125.
// Geometry = R16: 8x1 waves (32t x 256h), A direct-from-global + in-reg
// split, W-only prepass (2MB ws), epilogue P+swizzle, scan.

#define NB 64
#define NK 512
#define NT 512
#define NH 1024

#define TB 256     // t per block tile
#define HB 256     // h per block tile
#define KK 32      // k per step
#define NKT (NK / KK)   // 16

typedef _Float16 h8_t __attribute__((ext_vector_type(8)));
typedef float    f4_t __attribute__((ext_vector_type(4)));

#define AS1 __attribute__((address_space(1)))
#define AS3 __attribute__((address_space(3)))

__device__ __forceinline__ void async_copy16(const void* g, void* l) {
    __builtin_amdgcn_global_load_lds((const AS1 uint32_t*)g, (AS3 uint32_t*)l, 16, 0, 0);
}

__device__ __forceinline__ void wait_all_barrier() {
    __builtin_amdgcn_s_waitcnt(0);   // vmcnt(0) expcnt(0) lgkmcnt(0)
    __syncthreads();
}

// ---- W-only pre-pass: fp32 [512][1024] -> fp16 hi/lo in fragment order
__global__ __launch_bounds__(256) void split_w(
    const float* __restrict__ Wm, _Float16* __restrict__ whi,
    _Float16* __restrict__ wlo)
{
    const int tid = threadIdx.x;
    const int cq  = tid & 15;     // col quad 0..15
    const int u   = tid >> 4;     // row octet 0..15

    const int bx = blockIdx.x;    // 0..15
    const int by = blockIdx.y;    // 0..3
    const int C  = NH;
    const int col0 = bx * 64;
    const int row0 = by * 128;
    const int ktbase = by * 4;

    const float* s = Wm + (size_t)(row0 + u * 8) * C + col0 + cq * 4;

    f4_t v[8];
    #pragma unroll
    for (int j = 0; j < 8; ++j)
        v[j] = *(const f4_t*)(s + (size_t)j * C);

    const int kt = ktbase + (u >> 2);
    const int ck = u & 3;

    #pragma unroll
    for (int i = 0; i < 4; ++i) {
        h8_t hi, lo;
        #pragma unroll
        for (int j = 0; j < 8; ++j) {
            float f = v[j][i] * 64.0f;       // 2^6 pre-scale
            _Float16 hh = (_Float16)f;
            hi[j] = hh;
            lo[j] = (_Float16)(f - (float)hh);
        }
        const int col = col0 + cq * 4 + i;
        const int ckp = ck ^ ((col >> 1) & 3);
        const size_t off = ((size_t)kt * C + col) * 32 + (size_t)ckp * 8;
        *(h8_t*)(whi + off) = hi;
        *(h8_t*)(wlo + off) = lo;
    }
}

// ---------------- main fused kernel (R21: 4-ring, pair-barrier) ---------------
__global__ __launch_bounds__(512, 2) void fused_main(
    const float* __restrict__ X,
    const _Float16* __restrict__ whi, const _Float16* __restrict__ wlo,
    const float* __restrict__ bias, float* __restrict__ out)
{
    // B ring: 4 slots x [hi/lo][8192] halfs = 4 x 32 KB = 128 KB.
    __shared__ __align__(16) _Float16 SB[4][2][HB * KK];
    // Epilogue P[64][256] fp32 (64 KB) aliases slots 2+3 (contiguous).
    float* Pf = (float*)&SB[2][0][0];

    const int tid  = threadIdx.x;
    const int lane = tid & 63;
    const int wid  = tid >> 6;     // 0..7 = t octant (32 rows each)
    const int l15  = lane & 15;
    const int lq   = lane >> 4;    // 0..3

    const int b  = blockIdx.x;
    const int h0 = blockIdx.y * HB;

    // B fragment LDS offset (halfs); chunk swizzle matches prepass.
    const int sw   = (l15 >> 1) & 3;
    const int boff = (l15 * 4 + (lq ^ sw)) * 8;   // + ni*512, ni 0..15

    float hs = 0.0f, ys = 0.0f, bv = 0.0f;
    if (tid < HB) bv = bias[h0 + tid];

    const float INV_SCALE = 1.0f / 4096.0f;   // undo 2^6 x 2^6 operand scales

    auto stage_B = [&](int kt, int slot) {    // 4 DMA instrs / thread
        const _Float16* gb_hi = whi + ((size_t)kt * NH + h0) * KK;
        const _Float16* gb_lo = wlo + ((size_t)kt * NH + h0) * KK;
        #pragma unroll
        for (int c = 0; c < 2; ++c) {
            const int ch = tid + c * 512;
            async_copy16(gb_hi + ch * 8, &SB[slot][0][ch * 8]);
            async_copy16(gb_lo + ch * 8, &SB[slot][1][ch * 8]);
        }
    };

    // A fragment slice, direct from global (no dup across waves).
    // af[mi][j] = X[b][kt*32 + lq*8 + j][tt0 + wid*32 + mi*16 + l15]
    float af[2][8];
    auto loadA = [&](int tt0_, int kt) {
        const float* g = X + ((size_t)(b * NK + kt * KK + lq * 8)) * NT
                           + tt0_ + wid * 32 + l15;
        #pragma unroll
        for (int mi = 0; mi < 2; ++mi)
            #pragma unroll
            for (int j = 0; j < 8; ++j)
                af[mi][j] = g[(size_t)j * NT + mi * 16];
    };

    h8_t ah[2], al[2];
    auto convertA = [&]() {
        #pragma unroll
        for (int mi = 0; mi < 2; ++mi)
            #pragma unroll
            for (int j = 0; j < 8; ++j) {
                float f = af[mi][j] * 64.0f;     // bit-identical split
                _Float16 hh = (_Float16)f;
                ah[mi][j] = hh;
                al[mi][j] = (_Float16)(f - (float)hh);
            }
    };

    // one ni-column: 6 MFMAs, mode-outer / mi-inner (bit-exact per-acc order)
    f4_t acc[2][16];
    auto mfma_col = [&](int slot, int ni) {
        h8_t bh = *(const h8_t*)(&SB[slot][0][boff + ni * 512]);
        h8_t bl = *(const h8_t*)(&SB[slot][1][boff + ni * 512]);
        #pragma unroll
        for (int mi = 0; mi < 2; ++mi)
            acc[mi][ni] = __builtin_amdgcn_mfma_f32_16x16x32_f16(ah[mi], bh, acc[mi][ni], 0, 0, 0);
        #pragma unroll
        for (int mi = 0; mi < 2; ++mi)
            acc[mi][ni] = __builtin_amdgcn_mfma_f32_16x16x32_f16(ah[mi], bl, acc[mi][ni], 0, 0, 0);
        #pragma unroll
        for (int mi = 0; mi < 2; ++mi)
            acc[mi][ni] = __builtin_amdgcn_mfma_f32_16x16x32_f16(al[mi], bh, acc[mi][ni], 0, 0, 0);
    };

    // prologue: first two kt's B DMA into slots 0,1 + A(0) register loads
    stage_B(0, 0);
    stage_B(1, 1);
    loadA(0, 0);

    for (int tt0 = 0; tt0 < NT; tt0 += TB) {
        #pragma unroll
        for (int mi = 0; mi < 2; ++mi)
            #pragma unroll
            for (int ni = 0; ni < 16; ++ni) {
                f4_t z = {0.f, 0.f, 0.f, 0.f};
                acc[mi][ni] = z;
            }

        wait_all_barrier();   // prologue DMAs landed block-wide; af landed

        for (int kt = 0; kt < NKT; ++kt) {
            const int slot = kt & 3;

            convertA();                                    // af(kt) (compiler waits)
            if (kt + 1 < NKT) loadA(tt0, kt + 1);          // refill af
            if (kt + 2 < NKT) stage_B(kt + 2, (kt + 2) & 3);  // ring DMA

            __builtin_amdgcn_s_setprio(1);
            #pragma unroll
            for (int ni = 0; ni < 16; ++ni)
                mfma_col(slot, ni);
            __builtin_amdgcn_s_setprio(0);

            // ONE drain+barrier per pair: waves drift within the pair.
            if (kt & 1) wait_all_barrier();
        }

        // all slots dead here (final pair-barrier drained reads + DMAs).
        // Pre-issue next t-tile's B(0),B(1) into slots 0,1 (P is slots 2,3)
        // so DMA flies under the epilogue.
        if (tt0 + TB < NT) {
            stage_B(0, 0);
            stage_B(1, 1);
        }

        // epilogue: 4 t-subtiles x 64 rows; P[64][256] fp32 on slots 2+3.
        // Rows [sub*64, sub*64+64) from waves wid = 2*sub, 2*sub+1.
        // Swizzle col' = col ^ (((row>>2)&1)<<4); writer key (lq&1) ==
        // reader key ((m>>2)&1).
        #pragma unroll 1
        for (int sub = 0; sub < 4; ++sub) {
            if ((wid >> 1) == sub) {
                #pragma unroll
                for (int mi = 0; mi < 2; ++mi)
                    #pragma unroll
                    for (int ni = 0; ni < 16; ++ni)
                        #pragma unroll
                        for (int r2 = 0; r2 < 4; ++r2) {
                            const int rloc = (wid & 1) * 32 + mi * 16 + lq * 4 + r2;
                            const int col  = (ni * 16 + l15) ^ ((lq & 1) << 4);
                            Pf[rloc * 256 + col] = acc[mi][ni][r2] * INV_SCALE;
                        }
            }
            __syncthreads();
            if (tid < HB) {
                const int cc2 = tid;   // h within block tile, 0..255
                #pragma unroll 8
                for (int m = 0; m < 64; ++m) {
                    float p = Pf[m * 256 + (cc2 ^ (((m >> 2) & 1) << 4))];
                    float pre = p + 0.8f * hs * (1.0f - ys);
                    hs = pre > 0.0f ? pre : 0.0f;
                    float z = hs + bv;
                    ys = (z > 1.0f) ? z : 0.0f;
                }
            }
            __syncthreads();   // scan done before next sub overwrites P
        }

        // next t-tile's A loads after the epilogue (af regs dead during it).
        // Landing covered by the t-loop-top wait_all_barrier.
        if (tt0 + TB < NT)
            loadA(tt0 + TB, 0);
    }

    if (tid < HB)
        out[(size_t)b * NH + h0 + tid] = ys;
}

extern "C" void kernel_launch(void* const* d_in, const int* in_sizes, int n_in,
                              void* d_out, int out_size, void* d_ws, size_t ws_size,
                              hipStream_t stream) {
    const float* x    = (const float*)d_in[0];  // [64][512][512]
    const float* W    = (const float*)d_in[1];  // [512][1024]
    const float* bias = (const float*)d_in[2];  // [1024]
    float* out = (float*)d_out;

    _Float16* whi = (_Float16*)d_ws;            // 1 MB
    _Float16* wlo = whi + (size_t)NK * NH;      // 1 MB

    split_w<<<dim3(16, 4), 256, 0, stream>>>(W, whi, wlo);
    fused_main<<<dim3(NB, NH / HB), 512, 0, stream>>>(x, whi, wlo, bias, out);
}